// Round 11
// baseline (180.654 us; speedup 1.0000x reference)
//
#include <hip/hip_runtime.h>
#include <hip/hip_bf16.h>

#define N_NODES 100000
#define N_EDGES 1600000
#define F_IN 256
#define F_OUT 128
#define SCAN_BLOCKS ((N_NODES + 255) / 256)   // 391

#define N_BINS 128
#define RPB 782                  // rows per bin: 128*782 = 100096 >= 100000
#define L1_BLOCKS 256
#define L1_THREADS 512
#define L1_EDGES (N_EDGES / L1_BLOCKS)   // 6250 exactly
#define CNT_SIZE (N_BINS * L1_BLOCKS)    // 32768

typedef __attribute__((ext_vector_type(8))) short short8;
typedef __attribute__((ext_vector_type(4))) float f32x4;
typedef __attribute__((ext_vector_type(2))) float f32x2;
typedef __attribute__((ext_vector_type(2))) unsigned int uint2v;

static __device__ __forceinline__ unsigned short bf16b(float f) {
    __hip_bfloat16 h = __float2bfloat16(f);
    return *reinterpret_cast<unsigned short*>(&h);
}

// ---------- Kernel 1: pack W [256][128] f32 -> bf16 [ks(8)][kk(4)][col(128)][e(8)] ----------
__global__ void wprep_kernel(const float* __restrict__ W, unsigned short* __restrict__ Wsw) {
    int idx = blockIdx.x * 256 + threadIdx.x;   // 0..32767
    int e  = idx & 7;
    int col = (idx >> 3) & 127;
    int kk = (idx >> 10) & 3;
    int ks = idx >> 12;
    int k = ks * 32 + kk * 8 + e;
    Wsw[idx] = bf16b(W[k * 128 + col]);
}

// ---------- Kernel 2: pre = bf16(x @ W), MFMA, x staged via global_load_lds ----------
// R10 lesson: register prefetch can't beat regalloc (VGPR capped at 60, loads
// re-serialized, 61us latency-bound). Fix per §5: async global->LDS staging —
// no VGPR cost, 16KB in flight per wave. LDS writes are linear (HW constraint),
// so the XOR swizzle is applied on the GLOBAL source granule (lane^j) and the
// LDS read address (cb ^ l15<<4) — both-sides pattern; uniform bank use.
__global__ __launch_bounds__(256) void gemm_kernel(const float* __restrict__ x,
                                                   const unsigned short* __restrict__ Wsw,
                                                   unsigned short* __restrict__ preb) {
    extern __shared__ char sx[];                 // 64 KB: [64 rows][1024 B], swizzled
    const int lane = threadIdx.x & 63;
    const int wave = threadIdx.x >> 6;
    const int m0 = blockIdx.x * 64 + wave * 16;
    const int l15 = lane & 15;
    const int kk = lane >> 4;

    // Stage this wave's 16 rows, one row (1 KB = 64 lanes x 16 B) per instruction.
    {
        char* lbase = sx + wave * 16384;
#pragma unroll
        for (int j = 0; j < 16; ++j) {
            int r = m0 + j;
            if (r > N_NODES - 1) r = N_NODES - 1;        // clamp; stores guarded
            const char* gsrc = reinterpret_cast<const char*>(x + (size_t)r * F_IN)
                             + ((lane ^ j) << 4);        // pre-swizzled source granule
            __builtin_amdgcn_global_load_lds(
                (const __attribute__((address_space(1))) void*)gsrc,
                (__attribute__((address_space(3))) void*)(lbase + j * 1024),
                16, 0, 0);
        }
    }
    __syncthreads();                                     // drains vmcnt before reads

    f32x4 acc[8];
#pragma unroll
    for (int i = 0; i < 8; ++i) acc[i] = (f32x4){0.f, 0.f, 0.f, 0.f};

    const char* swb = sx + wave * 16384 + l15 * 1024;
    const int sw = l15 << 4;
#pragma unroll
    for (int ks = 0; ks < 8; ++ks) {
        const int cb = ks * 128 + kk * 32;               // byte col of this lane's 8 f32
        float4 fa = *reinterpret_cast<const float4*>(swb + ((cb) ^ sw));
        float4 fb = *reinterpret_cast<const float4*>(swb + ((cb + 16) ^ sw));
        short8 a;
        a[0] = (short)bf16b(fa.x); a[1] = (short)bf16b(fa.y);
        a[2] = (short)bf16b(fa.z); a[3] = (short)bf16b(fa.w);
        a[4] = (short)bf16b(fb.x); a[5] = (short)bf16b(fb.y);
        a[6] = (short)bf16b(fb.z); a[7] = (short)bf16b(fb.w);
        const short8* wv = reinterpret_cast<const short8*>(Wsw) + ((ks * 4 + kk) * 128 + l15);
#pragma unroll
        for (int nf = 0; nf < 8; ++nf) {
            short8 b = wv[nf * 16];
            acc[nf] = __builtin_amdgcn_mfma_f32_16x16x32_bf16(a, b, acc[nf], 0, 0, 0);
        }
    }

    // C/D layout: col = lane&15, row = (lane>>4)*4 + reg
    const int rbase = m0 + (lane >> 4) * 4;
#pragma unroll
    for (int nf = 0; nf < 8; ++nf) {
        int cc = nf * 16 + l15;
#pragma unroll
        for (int reg = 0; reg < 4; ++reg) {
            int rr = rbase + reg;
            if (rr < N_NODES) preb[(long)rr * F_OUT + cc] = bf16b(acc[nf][reg]);
        }
    }
}

// ---------- passA: per-(bin, block) counts — NO global atomics at all ----------
__global__ __launch_bounds__(L1_THREADS) void passA_kernel(const int* __restrict__ row,
                                                           int* __restrict__ cnt) {
    __shared__ int h[N_BINS];
    if (threadIdx.x < N_BINS) h[threadIdx.x] = 0;
    __syncthreads();
    const int g = blockIdx.x;
    const int base = g * L1_EDGES;
    for (int i = threadIdx.x; i < L1_EDGES; i += L1_THREADS) {
        int r = __builtin_nontemporal_load(row + base + i);
        atomicAdd(&h[r / RPB], 1);                   // LDS only
    }
    __syncthreads();
    if (threadIdx.x < N_BINS)
        cnt[threadIdx.x * L1_BLOCKS + g] = h[threadIdx.x];   // bin-major regions
}

// ---------- scan32768: exclusive scan of cnt[128][256] -> off[32769] ----------
__global__ void scan32768_kernel(const int* __restrict__ cnt, int* __restrict__ off) {
    __shared__ int tmp[1024];
    int t = threadIdx.x;                             // 1024 threads x 32 elems
    const int4* c4 = reinterpret_cast<const int4*>(cnt);
    int sum = 0;
#pragma unroll
    for (int j = 0; j < 8; ++j) {
        int4 v = c4[t * 8 + j];
        sum += v.x + v.y + v.z + v.w;
    }
    tmp[t] = sum;
    __syncthreads();
#pragma unroll
    for (int o = 1; o < 1024; o <<= 1) {
        int u = (t >= o) ? tmp[t - o] : 0;
        __syncthreads();
        tmp[t] += u;
        __syncthreads();
    }
    int base = tmp[t] - sum;                         // exclusive over threads
#pragma unroll
    for (int j = 0; j < 8; ++j) {
        int4 v = c4[t * 8 + j];
        off[t * 32 + j * 4 + 0] = base; base += v.x;
        off[t * 32 + j * 4 + 1] = base; base += v.y;
        off[t * 32 + j * 4 + 2] = base; base += v.z;
        off[t * 32 + j * 4 + 3] = base; base += v.w;
    }
    if (t == 1023) off[CNT_SIZE] = base;             // = N_EDGES
}

// ---------- passB: append to pre-reserved (bin, block) sub-regions; LDS-only cursors ----------
__global__ __launch_bounds__(L1_THREADS) void passB_kernel(const int* __restrict__ row,
                                                           const int* __restrict__ col,
                                                           const float* __restrict__ vals,
                                                           const int* __restrict__ off,
                                                           unsigned* __restrict__ packed,
                                                           unsigned short* __restrict__ valh) {
    __shared__ int cur[N_BINS];
    const int g = blockIdx.x;
    if (threadIdx.x < N_BINS) cur[threadIdx.x] = off[threadIdx.x * L1_BLOCKS + g];
    __syncthreads();
    const int base = g * L1_EDGES;
    for (int i = threadIdx.x; i < L1_EDGES; i += L1_THREADS) {
        int e = base + i;
        int r = __builtin_nontemporal_load(row + e);
        int c = __builtin_nontemporal_load(col + e);
        float v = __builtin_nontemporal_load(vals + e);
        int bin = r / RPB;
        int lr = r - bin * RPB;                      // < 782, 10 bits
        int pos = atomicAdd(&cur[bin], 1);           // LDS atomic
        packed[pos] = (unsigned)c | ((unsigned)lr << 17);
        valh[pos] = bf16b(v);
    }
}

// ---------- bin_deg: per-bin degree from the binned stream; zero global atomics ----------
__global__ __launch_bounds__(1024) void bin_deg_kernel(const unsigned* __restrict__ packed,
                                                       const int* __restrict__ off,
                                                       int* __restrict__ deg) {
    __shared__ int h[RPB];
    const int b = blockIdx.x;
    const int rbase = b * RPB;
    const int nrows = min(RPB, N_NODES - rbase);
    for (int i = threadIdx.x; i < nrows; i += 1024) h[i] = 0;
    __syncthreads();
    const int lo = off[b * L1_BLOCKS];
    const int hi = off[(b + 1) * L1_BLOCKS];
    for (int i = lo + (int)threadIdx.x; i < hi; i += 1024) {
        unsigned p = __builtin_nontemporal_load(packed + i);
        atomicAdd(&h[p >> 17], 1);                   // LDS atomic
    }
    __syncthreads();
    for (int i = threadIdx.x; i < nrows; i += 1024) deg[rbase + i] = h[i];
}

// ---------- row_start scans ----------
__global__ void scan_block_kernel(const int* __restrict__ deg, int* __restrict__ row_start,
                                  int* __restrict__ bsums) {
    __shared__ int tmp[256];
    int t = threadIdx.x;
    int i = blockIdx.x * 256 + t;
    int d = (i < N_NODES) ? deg[i] : 0;
    tmp[t] = d;
    __syncthreads();
#pragma unroll
    for (int o = 1; o < 256; o <<= 1) {
        int v = (t >= o) ? tmp[t - o] : 0;
        __syncthreads();
        tmp[t] += v;
        __syncthreads();
    }
    if (i < N_NODES) row_start[i] = tmp[t] - d;
    if (t == 255) bsums[blockIdx.x] = tmp[255];
}

__global__ void scan_bsums_kernel(int* __restrict__ bsums) {
    __shared__ int tmp[512];
    int t = threadIdx.x;
    int v = (t < SCAN_BLOCKS) ? bsums[t] : 0;
    tmp[t] = v;
    __syncthreads();
#pragma unroll
    for (int o = 1; o < 512; o <<= 1) {
        int u = (t >= o) ? tmp[t - o] : 0;
        __syncthreads();
        tmp[t] += u;
        __syncthreads();
    }
    bsums[t] = tmp[t] - v;
}

__global__ void scan_add_kernel(int* __restrict__ row_start, const int* __restrict__ bsums) {
    int i = blockIdx.x * 256 + threadIdx.x;
    if (i < N_NODES) {
        row_start[i] = row_start[i] + bsums[blockIdx.x];
        if (i == N_NODES - 1) row_start[N_NODES] = N_EDGES;
    }
}

// ---------- csr_place: ONE block per bin; LDS row-cursors; single-CU region ownership ----------
__global__ __launch_bounds__(1024) void csr_place_kernel(const unsigned* __restrict__ packed,
                                                         const unsigned short* __restrict__ valh,
                                                         const int* __restrict__ off,
                                                         const int* __restrict__ row_start,
                                                         uint2v* __restrict__ edges) {
    __shared__ int cur[RPB];
    const int b = blockIdx.x;
    const int rbase = b * RPB;
    const int nrows = min(RPB, N_NODES - rbase);
    for (int i = threadIdx.x; i < nrows; i += 1024) cur[i] = row_start[rbase + i];
    __syncthreads();
    const int lo = off[b * L1_BLOCKS];
    const int hi = off[(b + 1) * L1_BLOCKS];         // off[32768] = N_EDGES for b=127
    for (int i = lo + (int)threadIdx.x; i < hi; i += 1024) {
        unsigned p = __builtin_nontemporal_load(packed + i);
        unsigned short vh = __builtin_nontemporal_load(valh + i);
        int lr = (int)(p >> 17);
        int c = (int)(p & 0x1FFFFu);
        int pos = atomicAdd(&cur[lr], 1);            // LDS atomic
        edges[pos] = (uint2v){(unsigned)c, ((unsigned)vh) << 16};
    }
}

// ---------- spmm: readlane edge broadcast + 8-deep unconditional gather MLP ----------
__global__ __launch_bounds__(256) void spmm_csr_kernel(
    const unsigned short* __restrict__ preb, const int* __restrict__ row_start,
    const uint2v* __restrict__ edges, const float* __restrict__ bias,
    float* __restrict__ out) {
    const int lane = threadIdx.x & 63;
    const int r = blockIdx.x * 4 + (threadIdx.x >> 6);
    const int s = row_start[r];
    const int t = row_start[r + 1];
    const int n = t - s;
    float a0 = 0.f, a1 = 0.f;

    // One coalesced load grabs up to 64 edges of this row; padded lanes carry
    // {col=0, val=0} so the inner loop needs no bounds checks (0-contribution).
    uint2v ev = (uint2v){0u, 0u};
    if (lane < n) ev = edges[s + lane];
    const int nn = n < 64 ? n : 64;
    for (int j0 = 0; j0 < nn; j0 += 8) {
#pragma unroll
        for (int jj = 0; jj < 8; ++jj) {
            int j = j0 + jj;
            unsigned c = (unsigned)__builtin_amdgcn_readlane((int)ev.x, j);
            unsigned vb = (unsigned)__builtin_amdgcn_readlane((int)ev.y, j);
            unsigned g = *reinterpret_cast<const unsigned*>(preb + (size_t)c * F_OUT + lane * 2);
            float v = __uint_as_float(vb);
            a0 += v * __uint_as_float(g << 16);
            a1 += v * __uint_as_float(g & 0xFFFF0000u);
        }
    }
    // Rare n > 64 fallback (cached broadcast loads).
    for (int e = s + 64; e < t; ++e) {
        uint2v cv = edges[e];
        float v = __uint_as_float(cv.y);
        unsigned g = *reinterpret_cast<const unsigned*>(preb + (size_t)cv.x * F_OUT + lane * 2);
        a0 += v * __uint_as_float(g << 16);
        a1 += v * __uint_as_float(g & 0xFFFF0000u);
    }

    float2 bb = *reinterpret_cast<const float2*>(bias + lane * 2);
    f32x2 o;
    o.x = fmaxf(a0 + bb.x, 0.f);
    o.y = fmaxf(a1 + bb.y, 0.f);
    __builtin_nontemporal_store(o, reinterpret_cast<f32x2*>(out + (size_t)r * F_OUT + lane * 2));
}

extern "C" void kernel_launch(void* const* d_in, const int* in_sizes, int n_in,
                              void* d_out, int out_size, void* d_ws, size_t ws_size,
                              hipStream_t stream) {
    const float* x    = (const float*)d_in[0];
    const float* W    = (const float*)d_in[1];
    const float* b    = (const float*)d_in[2];
    const float* vals = (const float*)d_in[3];
    const int*   row  = (const int*)d_in[4];
    const int*   col  = (const int*)d_in[5];
    float* out = (float*)d_out;

    // Workspace layout, total 49,531,904 B (<= 51,265,536 proven available in R1):
    char* ws = (char*)d_ws;
    unsigned short* preb      = (unsigned short*)(ws);                 // 25,600,000
    unsigned short* Wsw       = (unsigned short*)(ws + 25600000);      //     65,536
    int*            row_start = (int*)(ws + 25665536);                 //    400,016
    int*            deg       = (int*)(ws + 26065568);                 //    400,000
    int*            bsums     = (int*)(ws + 26465568);                 //      4,096
    int*            cnt       = (int*)(ws + 26469664);                 //    131,072 (16B-aligned)
    int*            off       = (int*)(ws + 26600736);                 //    131,076 (+pad)
    unsigned*       packed    = (unsigned*)(ws + 26731904);            //  6,400,000
    unsigned short* valh      = (unsigned short*)(ws + 33131904);      //  3,200,000
    uint2v*         edges     = (uint2v*)(ws + 36331904);              // 12,800,000 (8B-aligned)

    wprep_kernel<<<128, 256, 0, stream>>>(W, Wsw);
    gemm_kernel<<<(N_NODES + 63) / 64, 256, 65536, stream>>>(x, Wsw, preb);

    passA_kernel<<<L1_BLOCKS, L1_THREADS, 0, stream>>>(row, cnt);
    scan32768_kernel<<<1, 1024, 0, stream>>>(cnt, off);
    passB_kernel<<<L1_BLOCKS, L1_THREADS, 0, stream>>>(row, col, vals, off, packed, valh);

    bin_deg_kernel<<<N_BINS, 1024, 0, stream>>>(packed, off, deg);
    scan_block_kernel<<<SCAN_BLOCKS, 256, 0, stream>>>(deg, row_start, bsums);
    scan_bsums_kernel<<<1, 512, 0, stream>>>(bsums);
    scan_add_kernel<<<SCAN_BLOCKS, 256, 0, stream>>>(row_start, bsums);

    csr_place_kernel<<<N_BINS, 1024, 0, stream>>>(packed, valh, off, row_start, edges);

    spmm_csr_kernel<<<N_NODES / 4, 256, 0, stream>>>(preb, row_start, edges, b, out);
}

// Round 12
// 169.833 us; speedup vs baseline: 1.0637x; 1.0637x over previous
//
#include <hip/hip_runtime.h>
#include <hip/hip_bf16.h>

#define N_NODES 100000
#define N_EDGES 1600000
#define F_IN 256
#define F_OUT 128
#define SCAN_BLOCKS ((N_NODES + 255) / 256)   // 391

#define N_BINS 128
#define RPB 782                  // rows per bin: 128*782 = 100096 >= 100000
#define L1_BLOCKS 256
#define L1_THREADS 512
#define L1_EDGES (N_EDGES / L1_BLOCKS)   // 6250 exactly
#define CNT_SIZE (N_BINS * L1_BLOCKS)    // 32768

typedef __attribute__((ext_vector_type(8))) short short8;
typedef __attribute__((ext_vector_type(4))) float f32x4;
typedef __attribute__((ext_vector_type(2))) float f32x2;
typedef __attribute__((ext_vector_type(2))) unsigned int uint2v;

static __device__ __forceinline__ unsigned short bf16b(float f) {
    __hip_bfloat16 h = __float2bfloat16(f);
    return *reinterpret_cast<unsigned short*>(&h);
}

// ---------- Kernel 1: pack W [256][128] f32 -> bf16 [ks(8)][kk(4)][col(128)][e(8)] ----------
__global__ void wprep_kernel(const float* __restrict__ W, unsigned short* __restrict__ Wsw) {
    int idx = blockIdx.x * 256 + threadIdx.x;   // 0..32767
    int e  = idx & 7;
    int col = (idx >> 3) & 127;
    int kk = (idx >> 10) & 3;
    int ks = idx >> 12;
    int k = ks * 32 + kk * 8 + e;
    Wsw[idx] = bf16b(W[k * 128 + col]);
}

// ---------- Kernel 2: pre = bf16(x @ W) — single-wave blocks, 16 rows, 16KB LDS ----------
// R11 lesson: 64KB-tile blocks -> 2 blocks/CU, phased stage/compute with nothing
// to overlap (62us, VALU 7%). Fix: 10 independent 1-wave pipelines per CU
// (16KB LDS each, grid = N/16 = 6250); ~half stage while ~half compute, no
// barriers across waves. Swizzle: source granule lane^j, read addr ^ (l15<<4)
// (both-sides pattern, verified conflict-free in R11).
__global__ __launch_bounds__(64) void gemm_kernel(const float* __restrict__ x,
                                                  const unsigned short* __restrict__ Wsw,
                                                  unsigned short* __restrict__ preb) {
    __shared__ char sx[16384];                   // [16 rows][1024 B], swizzled
    const int lane = threadIdx.x;                // 0..63
    const int m0 = blockIdx.x * 16;              // 6250*16 = 100000 exactly: no guards
    const int l15 = lane & 15;
    const int kk = lane >> 4;

    // Stage 16 rows, one row (1 KB = 64 lanes x 16 B) per instruction.
#pragma unroll
    for (int j = 0; j < 16; ++j) {
        const char* gsrc = reinterpret_cast<const char*>(x + (size_t)(m0 + j) * F_IN)
                         + ((lane ^ j) << 4);    // pre-swizzled source granule
        __builtin_amdgcn_global_load_lds(
            (const __attribute__((address_space(1))) void*)gsrc,
            (__attribute__((address_space(3))) void*)(sx + j * 1024),
            16, 0, 0);
    }
    __syncthreads();                             // 1-wave block: just the vmcnt drain

    f32x4 acc[8];
#pragma unroll
    for (int i = 0; i < 8; ++i) acc[i] = (f32x4){0.f, 0.f, 0.f, 0.f};

    const char* swb = sx + l15 * 1024;
    const int sw = l15 << 4;
#pragma unroll
    for (int ks = 0; ks < 8; ++ks) {
        const int cb = ks * 128 + kk * 32;       // byte col of this lane's 8 f32
        float4 fa = *reinterpret_cast<const float4*>(swb + ((cb) ^ sw));
        float4 fb = *reinterpret_cast<const float4*>(swb + ((cb + 16) ^ sw));
        short8 a;
        a[0] = (short)bf16b(fa.x); a[1] = (short)bf16b(fa.y);
        a[2] = (short)bf16b(fa.z); a[3] = (short)bf16b(fa.w);
        a[4] = (short)bf16b(fb.x); a[5] = (short)bf16b(fb.y);
        a[6] = (short)bf16b(fb.z); a[7] = (short)bf16b(fb.w);
        const short8* wv = reinterpret_cast<const short8*>(Wsw) + ((ks * 4 + kk) * 128 + l15);
#pragma unroll
        for (int nf = 0; nf < 8; ++nf) {
            short8 b = wv[nf * 16];
            acc[nf] = __builtin_amdgcn_mfma_f32_16x16x32_bf16(a, b, acc[nf], 0, 0, 0);
        }
    }

    // C/D layout: col = lane&15, row = (lane>>4)*4 + reg
    const int rbase = m0 + (lane >> 4) * 4;
#pragma unroll
    for (int nf = 0; nf < 8; ++nf) {
        int cc = nf * 16 + l15;
#pragma unroll
        for (int reg = 0; reg < 4; ++reg) {
            preb[(long)(rbase + reg) * F_OUT + cc] = bf16b(acc[nf][reg]);
        }
    }
}

// ---------- passA: per-(bin, block) counts — NO global atomics at all ----------
__global__ __launch_bounds__(L1_THREADS) void passA_kernel(const int* __restrict__ row,
                                                           int* __restrict__ cnt) {
    __shared__ int h[N_BINS];
    if (threadIdx.x < N_BINS) h[threadIdx.x] = 0;
    __syncthreads();
    const int g = blockIdx.x;
    const int base = g * L1_EDGES;
    for (int i = threadIdx.x; i < L1_EDGES; i += L1_THREADS) {
        int r = __builtin_nontemporal_load(row + base + i);
        atomicAdd(&h[r / RPB], 1);                   // LDS only
    }
    __syncthreads();
    if (threadIdx.x < N_BINS)
        cnt[threadIdx.x * L1_BLOCKS + g] = h[threadIdx.x];   // bin-major regions
}

// ---------- scan32768: exclusive scan of cnt[128][256] -> off[32769] ----------
__global__ void scan32768_kernel(const int* __restrict__ cnt, int* __restrict__ off) {
    __shared__ int tmp[1024];
    int t = threadIdx.x;                             // 1024 threads x 32 elems
    const int4* c4 = reinterpret_cast<const int4*>(cnt);
    int sum = 0;
#pragma unroll
    for (int j = 0; j < 8; ++j) {
        int4 v = c4[t * 8 + j];
        sum += v.x + v.y + v.z + v.w;
    }
    tmp[t] = sum;
    __syncthreads();
#pragma unroll
    for (int o = 1; o < 1024; o <<= 1) {
        int u = (t >= o) ? tmp[t - o] : 0;
        __syncthreads();
        tmp[t] += u;
        __syncthreads();
    }
    int base = tmp[t] - sum;                         // exclusive over threads
#pragma unroll
    for (int j = 0; j < 8; ++j) {
        int4 v = c4[t * 8 + j];
        off[t * 32 + j * 4 + 0] = base; base += v.x;
        off[t * 32 + j * 4 + 1] = base; base += v.y;
        off[t * 32 + j * 4 + 2] = base; base += v.z;
        off[t * 32 + j * 4 + 3] = base; base += v.w;
    }
    if (t == 1023) off[CNT_SIZE] = base;             // = N_EDGES
}

// ---------- passB: append to pre-reserved (bin, block) sub-regions; LDS-only cursors ----------
__global__ __launch_bounds__(L1_THREADS) void passB_kernel(const int* __restrict__ row,
                                                           const int* __restrict__ col,
                                                           const float* __restrict__ vals,
                                                           const int* __restrict__ off,
                                                           unsigned* __restrict__ packed,
                                                           unsigned short* __restrict__ valh) {
    __shared__ int cur[N_BINS];
    const int g = blockIdx.x;
    if (threadIdx.x < N_BINS) cur[threadIdx.x] = off[threadIdx.x * L1_BLOCKS + g];
    __syncthreads();
    const int base = g * L1_EDGES;
    for (int i = threadIdx.x; i < L1_EDGES; i += L1_THREADS) {
        int e = base + i;
        int r = __builtin_nontemporal_load(row + e);
        int c = __builtin_nontemporal_load(col + e);
        float v = __builtin_nontemporal_load(vals + e);
        int bin = r / RPB;
        int lr = r - bin * RPB;                      // < 782, 10 bits
        int pos = atomicAdd(&cur[bin], 1);           // LDS atomic
        packed[pos] = (unsigned)c | ((unsigned)lr << 17);
        valh[pos] = bf16b(v);
    }
}

// ---------- bin_deg: per-bin degree from the binned stream; zero global atomics ----------
__global__ __launch_bounds__(1024) void bin_deg_kernel(const unsigned* __restrict__ packed,
                                                       const int* __restrict__ off,
                                                       int* __restrict__ deg) {
    __shared__ int h[RPB];
    const int b = blockIdx.x;
    const int rbase = b * RPB;
    const int nrows = min(RPB, N_NODES - rbase);
    for (int i = threadIdx.x; i < nrows; i += 1024) h[i] = 0;
    __syncthreads();
    const int lo = off[b * L1_BLOCKS];
    const int hi = off[(b + 1) * L1_BLOCKS];
    for (int i = lo + (int)threadIdx.x; i < hi; i += 1024) {
        unsigned p = __builtin_nontemporal_load(packed + i);
        atomicAdd(&h[p >> 17], 1);                   // LDS atomic
    }
    __syncthreads();
    for (int i = threadIdx.x; i < nrows; i += 1024) deg[rbase + i] = h[i];
}

// ---------- row_start scans ----------
__global__ void scan_block_kernel(const int* __restrict__ deg, int* __restrict__ row_start,
                                  int* __restrict__ bsums) {
    __shared__ int tmp[256];
    int t = threadIdx.x;
    int i = blockIdx.x * 256 + t;
    int d = (i < N_NODES) ? deg[i] : 0;
    tmp[t] = d;
    __syncthreads();
#pragma unroll
    for (int o = 1; o < 256; o <<= 1) {
        int v = (t >= o) ? tmp[t - o] : 0;
        __syncthreads();
        tmp[t] += v;
        __syncthreads();
    }
    if (i < N_NODES) row_start[i] = tmp[t] - d;
    if (t == 255) bsums[blockIdx.x] = tmp[255];
}

__global__ void scan_bsums_kernel(int* __restrict__ bsums) {
    __shared__ int tmp[512];
    int t = threadIdx.x;
    int v = (t < SCAN_BLOCKS) ? bsums[t] : 0;
    tmp[t] = v;
    __syncthreads();
#pragma unroll
    for (int o = 1; o < 512; o <<= 1) {
        int u = (t >= o) ? tmp[t - o] : 0;
        __syncthreads();
        tmp[t] += u;
        __syncthreads();
    }
    bsums[t] = tmp[t] - v;
}

__global__ void scan_add_kernel(int* __restrict__ row_start, const int* __restrict__ bsums) {
    int i = blockIdx.x * 256 + threadIdx.x;
    if (i < N_NODES) {
        row_start[i] = row_start[i] + bsums[blockIdx.x];
        if (i == N_NODES - 1) row_start[N_NODES] = N_EDGES;
    }
}

// ---------- csr_place: ONE block per bin; LDS row-cursors; single-CU region ownership ----------
__global__ __launch_bounds__(1024) void csr_place_kernel(const unsigned* __restrict__ packed,
                                                         const unsigned short* __restrict__ valh,
                                                         const int* __restrict__ off,
                                                         const int* __restrict__ row_start,
                                                         uint2v* __restrict__ edges) {
    __shared__ int cur[RPB];
    const int b = blockIdx.x;
    const int rbase = b * RPB;
    const int nrows = min(RPB, N_NODES - rbase);
    for (int i = threadIdx.x; i < nrows; i += 1024) cur[i] = row_start[rbase + i];
    __syncthreads();
    const int lo = off[b * L1_BLOCKS];
    const int hi = off[(b + 1) * L1_BLOCKS];         // off[32768] = N_EDGES for b=127
    for (int i = lo + (int)threadIdx.x; i < hi; i += 1024) {
        unsigned p = __builtin_nontemporal_load(packed + i);
        unsigned short vh = __builtin_nontemporal_load(valh + i);
        int lr = (int)(p >> 17);
        int c = (int)(p & 0x1FFFFu);
        int pos = atomicAdd(&cur[lr], 1);            // LDS atomic
        edges[pos] = (uint2v){(unsigned)c, ((unsigned)vh) << 16};
    }
}

// ---------- spmm: readlane edge broadcast + 8-deep unconditional gather MLP ----------
__global__ __launch_bounds__(256) void spmm_csr_kernel(
    const unsigned short* __restrict__ preb, const int* __restrict__ row_start,
    const uint2v* __restrict__ edges, const float* __restrict__ bias,
    float* __restrict__ out) {
    const int lane = threadIdx.x & 63;
    const int r = blockIdx.x * 4 + (threadIdx.x >> 6);
    const int s = row_start[r];
    const int t = row_start[r + 1];
    const int n = t - s;
    float a0 = 0.f, a1 = 0.f;

    // One coalesced load grabs up to 64 edges of this row; padded lanes carry
    // {col=0, val=0} so the inner loop needs no bounds checks (0-contribution).
    uint2v ev = (uint2v){0u, 0u};
    if (lane < n) ev = edges[s + lane];
    const int nn = n < 64 ? n : 64;
    for (int j0 = 0; j0 < nn; j0 += 8) {
#pragma unroll
        for (int jj = 0; jj < 8; ++jj) {
            int j = j0 + jj;
            unsigned c = (unsigned)__builtin_amdgcn_readlane((int)ev.x, j);
            unsigned vb = (unsigned)__builtin_amdgcn_readlane((int)ev.y, j);
            unsigned g = *reinterpret_cast<const unsigned*>(preb + (size_t)c * F_OUT + lane * 2);
            float v = __uint_as_float(vb);
            a0 += v * __uint_as_float(g << 16);
            a1 += v * __uint_as_float(g & 0xFFFF0000u);
        }
    }
    // Rare n > 64 fallback (cached broadcast loads).
    for (int e = s + 64; e < t; ++e) {
        uint2v cv = edges[e];
        float v = __uint_as_float(cv.y);
        unsigned g = *reinterpret_cast<const unsigned*>(preb + (size_t)cv.x * F_OUT + lane * 2);
        a0 += v * __uint_as_float(g << 16);
        a1 += v * __uint_as_float(g & 0xFFFF0000u);
    }

    float2 bb = *reinterpret_cast<const float2*>(bias + lane * 2);
    f32x2 o;
    o.x = fmaxf(a0 + bb.x, 0.f);
    o.y = fmaxf(a1 + bb.y, 0.f);
    __builtin_nontemporal_store(o, reinterpret_cast<f32x2*>(out + (size_t)r * F_OUT + lane * 2));
}

extern "C" void kernel_launch(void* const* d_in, const int* in_sizes, int n_in,
                              void* d_out, int out_size, void* d_ws, size_t ws_size,
                              hipStream_t stream) {
    const float* x    = (const float*)d_in[0];
    const float* W    = (const float*)d_in[1];
    const float* b    = (const float*)d_in[2];
    const float* vals = (const float*)d_in[3];
    const int*   row  = (const int*)d_in[4];
    const int*   col  = (const int*)d_in[5];
    float* out = (float*)d_out;

    // Workspace layout, total 49,531,904 B (<= 51,265,536 proven available in R1):
    char* ws = (char*)d_ws;
    unsigned short* preb      = (unsigned short*)(ws);                 // 25,600,000
    unsigned short* Wsw       = (unsigned short*)(ws + 25600000);      //     65,536
    int*            row_start = (int*)(ws + 25665536);                 //    400,016
    int*            deg       = (int*)(ws + 26065568);                 //    400,000
    int*            bsums     = (int*)(ws + 26465568);                 //      4,096
    int*            cnt       = (int*)(ws + 26469664);                 //    131,072 (16B-aligned)
    int*            off       = (int*)(ws + 26600736);                 //    131,076 (+pad)
    unsigned*       packed    = (unsigned*)(ws + 26731904);            //  6,400,000
    unsigned short* valh      = (unsigned short*)(ws + 33131904);      //  3,200,000
    uint2v*         edges     = (uint2v*)(ws + 36331904);              // 12,800,000 (8B-aligned)

    wprep_kernel<<<128, 256, 0, stream>>>(W, Wsw);
    gemm_kernel<<<N_NODES / 16, 64, 0, stream>>>(x, Wsw, preb);

    passA_kernel<<<L1_BLOCKS, L1_THREADS, 0, stream>>>(row, cnt);
    scan32768_kernel<<<1, 1024, 0, stream>>>(cnt, off);
    passB_kernel<<<L1_BLOCKS, L1_THREADS, 0, stream>>>(row, col, vals, off, packed, valh);

    bin_deg_kernel<<<N_BINS, 1024, 0, stream>>>(packed, off, deg);
    scan_block_kernel<<<SCAN_BLOCKS, 256, 0, stream>>>(deg, row_start, bsums);
    scan_bsums_kernel<<<1, 512, 0, stream>>>(bsums);
    scan_add_kernel<<<SCAN_BLOCKS, 256, 0, stream>>>(row_start, bsums);

    csr_place_kernel<<<N_BINS, 1024, 0, stream>>>(packed, valh, off, row_start, edges);

    spmm_csr_kernel<<<N_NODES / 4, 256, 0, stream>>>(preb, row_start, edges, b, out);
}

// Round 13
// 169.221 us; speedup vs baseline: 1.0676x; 1.0036x over previous
//
#include <hip/hip_runtime.h>
#include <hip/hip_bf16.h>

#define N_NODES 100000
#define N_EDGES 1600000
#define F_IN 256
#define F_OUT 128
#define SCAN_BLOCKS ((N_NODES + 255) / 256)   // 391

#define N_BINS 128
#define RPB 782                  // rows per bin: 128*782 = 100096 >= 100000
#define L1_BLOCKS 256
#define L1_THREADS 512
#define L1_EDGES (N_EDGES / L1_BLOCKS)   // 6250 exactly
#define CNT_SIZE (N_BINS * L1_BLOCKS)    // 32768

typedef __attribute__((ext_vector_type(8))) short short8;
typedef __attribute__((ext_vector_type(4))) float f32x4;
typedef __attribute__((ext_vector_type(2))) float f32x2;
typedef __attribute__((ext_vector_type(2))) unsigned int uint2v;

static __device__ __forceinline__ unsigned short bf16b(float f) {
    __hip_bfloat16 h = __float2bfloat16(f);
    return *reinterpret_cast<unsigned short*>(&h);
}

// ---------- Kernel 1: pack W [256][128] f32 -> bf16 [ks(8)][kk(4)][col(128)][e(8)] ----------
__global__ void wprep_kernel(const float* __restrict__ W, unsigned short* __restrict__ Wsw) {
    int idx = blockIdx.x * 256 + threadIdx.x;   // 0..32767
    int e  = idx & 7;
    int col = (idx >> 3) & 127;
    int kk = (idx >> 10) & 3;
    int ks = idx >> 12;
    int k = ks * 32 + kk * 8 + e;
    Wsw[idx] = bf16b(W[k * 128 + col]);
}

// ---------- Kernel 2: pre = bf16(x @ W) — single-wave blocks, 16 rows, 16KB LDS ----------
// 10 independent 1-wave pipelines per CU; stage via global_load_lds (linear LDS
// dest), source granule pre-swizzled lane^j, read addr ^ (l15<<4). R12: works.
__global__ __launch_bounds__(64) void gemm_kernel(const float* __restrict__ x,
                                                  const unsigned short* __restrict__ Wsw,
                                                  unsigned short* __restrict__ preb) {
    __shared__ char sx[16384];                   // [16 rows][1024 B], swizzled
    const int lane = threadIdx.x;                // 0..63
    const int m0 = blockIdx.x * 16;              // 6250*16 = 100000 exactly: no guards
    const int l15 = lane & 15;
    const int kk = lane >> 4;

#pragma unroll
    for (int j = 0; j < 16; ++j) {
        const char* gsrc = reinterpret_cast<const char*>(x + (size_t)(m0 + j) * F_IN)
                         + ((lane ^ j) << 4);    // pre-swizzled source granule
        __builtin_amdgcn_global_load_lds(
            (const __attribute__((address_space(1))) void*)gsrc,
            (__attribute__((address_space(3))) void*)(sx + j * 1024),
            16, 0, 0);
    }
    __syncthreads();                             // 1-wave block: just the vmcnt drain

    f32x4 acc[8];
#pragma unroll
    for (int i = 0; i < 8; ++i) acc[i] = (f32x4){0.f, 0.f, 0.f, 0.f};

    const char* swb = sx + l15 * 1024;
    const int sw = l15 << 4;
#pragma unroll
    for (int ks = 0; ks < 8; ++ks) {
        const int cb = ks * 128 + kk * 32;       // byte col of this lane's 8 f32
        float4 fa = *reinterpret_cast<const float4*>(swb + ((cb) ^ sw));
        float4 fb = *reinterpret_cast<const float4*>(swb + ((cb + 16) ^ sw));
        short8 a;
        a[0] = (short)bf16b(fa.x); a[1] = (short)bf16b(fa.y);
        a[2] = (short)bf16b(fa.z); a[3] = (short)bf16b(fa.w);
        a[4] = (short)bf16b(fb.x); a[5] = (short)bf16b(fb.y);
        a[6] = (short)bf16b(fb.z); a[7] = (short)bf16b(fb.w);
        const short8* wv = reinterpret_cast<const short8*>(Wsw) + ((ks * 4 + kk) * 128 + l15);
#pragma unroll
        for (int nf = 0; nf < 8; ++nf) {
            short8 b = wv[nf * 16];
            acc[nf] = __builtin_amdgcn_mfma_f32_16x16x32_bf16(a, b, acc[nf], 0, 0, 0);
        }
    }

    // C/D layout: col = lane&15, row = (lane>>4)*4 + reg
    const int rbase = m0 + (lane >> 4) * 4;
#pragma unroll
    for (int nf = 0; nf < 8; ++nf) {
        int cc = nf * 16 + l15;
#pragma unroll
        for (int reg = 0; reg < 4; ++reg) {
            preb[(long)(rbase + reg) * F_OUT + cc] = bf16b(acc[nf][reg]);
        }
    }
}

// ---------- passA: per-(bin, block) counts — NO global atomics at all ----------
__global__ __launch_bounds__(L1_THREADS) void passA_kernel(const int* __restrict__ row,
                                                           int* __restrict__ cnt) {
    __shared__ int h[N_BINS];
    if (threadIdx.x < N_BINS) h[threadIdx.x] = 0;
    __syncthreads();
    const int g = blockIdx.x;
    const int base = g * L1_EDGES;
    for (int i = threadIdx.x; i < L1_EDGES; i += L1_THREADS) {
        int r = __builtin_nontemporal_load(row + base + i);
        atomicAdd(&h[r / RPB], 1);                   // LDS only
    }
    __syncthreads();
    if (threadIdx.x < N_BINS)
        cnt[threadIdx.x * L1_BLOCKS + g] = h[threadIdx.x];   // bin-major regions
}

// ---------- scan32768: exclusive scan of cnt[128][256] -> off[32769] ----------
__global__ void scan32768_kernel(const int* __restrict__ cnt, int* __restrict__ off) {
    __shared__ int tmp[1024];
    int t = threadIdx.x;                             // 1024 threads x 32 elems
    const int4* c4 = reinterpret_cast<const int4*>(cnt);
    int sum = 0;
#pragma unroll
    for (int j = 0; j < 8; ++j) {
        int4 v = c4[t * 8 + j];
        sum += v.x + v.y + v.z + v.w;
    }
    tmp[t] = sum;
    __syncthreads();
#pragma unroll
    for (int o = 1; o < 1024; o <<= 1) {
        int u = (t >= o) ? tmp[t - o] : 0;
        __syncthreads();
        tmp[t] += u;
        __syncthreads();
    }
    int base = tmp[t] - sum;                         // exclusive over threads
#pragma unroll
    for (int j = 0; j < 8; ++j) {
        int4 v = c4[t * 8 + j];
        off[t * 32 + j * 4 + 0] = base; base += v.x;
        off[t * 32 + j * 4 + 1] = base; base += v.y;
        off[t * 32 + j * 4 + 2] = base; base += v.z;
        off[t * 32 + j * 4 + 3] = base; base += v.w;
    }
    if (t == 1023) off[CNT_SIZE] = base;             // = N_EDGES
}

// ---------- passB: append to pre-reserved (bin, block) sub-regions; LDS-only cursors ----------
__global__ __launch_bounds__(L1_THREADS) void passB_kernel(const int* __restrict__ row,
                                                           const int* __restrict__ col,
                                                           const float* __restrict__ vals,
                                                           const int* __restrict__ off,
                                                           unsigned* __restrict__ packed,
                                                           unsigned short* __restrict__ valh) {
    __shared__ int cur[N_BINS];
    const int g = blockIdx.x;
    if (threadIdx.x < N_BINS) cur[threadIdx.x] = off[threadIdx.x * L1_BLOCKS + g];
    __syncthreads();
    const int base = g * L1_EDGES;
    for (int i = threadIdx.x; i < L1_EDGES; i += L1_THREADS) {
        int e = base + i;
        int r = __builtin_nontemporal_load(row + e);
        int c = __builtin_nontemporal_load(col + e);
        float v = __builtin_nontemporal_load(vals + e);
        int bin = r / RPB;
        int lr = r - bin * RPB;                      // < 782, 10 bits
        int pos = atomicAdd(&cur[bin], 1);           // LDS atomic
        packed[pos] = (unsigned)c | ((unsigned)lr << 17);
        valh[pos] = bf16b(v);
    }
}

// ---------- bin_deg: per-bin degree from the binned stream; zero global atomics ----------
__global__ __launch_bounds__(1024) void bin_deg_kernel(const unsigned* __restrict__ packed,
                                                       const int* __restrict__ off,
                                                       int* __restrict__ deg) {
    __shared__ int h[RPB];
    const int b = blockIdx.x;
    const int rbase = b * RPB;
    const int nrows = min(RPB, N_NODES - rbase);
    for (int i = threadIdx.x; i < nrows; i += 1024) h[i] = 0;
    __syncthreads();
    const int lo = off[b * L1_BLOCKS];
    const int hi = off[(b + 1) * L1_BLOCKS];
    for (int i = lo + (int)threadIdx.x; i < hi; i += 1024) {
        unsigned p = __builtin_nontemporal_load(packed + i);
        atomicAdd(&h[p >> 17], 1);                   // LDS atomic
    }
    __syncthreads();
    for (int i = threadIdx.x; i < nrows; i += 1024) deg[rbase + i] = h[i];
}

// ---------- row_start scans ----------
__global__ void scan_block_kernel(const int* __restrict__ deg, int* __restrict__ row_start,
                                  int* __restrict__ bsums) {
    __shared__ int tmp[256];
    int t = threadIdx.x;
    int i = blockIdx.x * 256 + t;
    int d = (i < N_NODES) ? deg[i] : 0;
    tmp[t] = d;
    __syncthreads();
#pragma unroll
    for (int o = 1; o < 256; o <<= 1) {
        int v = (t >= o) ? tmp[t - o] : 0;
        __syncthreads();
        tmp[t] += v;
        __syncthreads();
    }
    if (i < N_NODES) row_start[i] = tmp[t] - d;
    if (t == 255) bsums[blockIdx.x] = tmp[255];
}

__global__ void scan_bsums_kernel(int* __restrict__ bsums) {
    __shared__ int tmp[512];
    int t = threadIdx.x;
    int v = (t < SCAN_BLOCKS) ? bsums[t] : 0;
    tmp[t] = v;
    __syncthreads();
#pragma unroll
    for (int o = 1; o < 512; o <<= 1) {
        int u = (t >= o) ? tmp[t - o] : 0;
        __syncthreads();
        tmp[t] += u;
        __syncthreads();
    }
    bsums[t] = tmp[t] - v;
}

__global__ void scan_add_kernel(int* __restrict__ row_start, const int* __restrict__ bsums) {
    int i = blockIdx.x * 256 + threadIdx.x;
    if (i < N_NODES) {
        row_start[i] = row_start[i] + bsums[blockIdx.x];
        if (i == N_NODES - 1) row_start[N_NODES] = N_EDGES;
    }
}

// ---------- csr_place: ONE block per bin; LDS row-cursors; single-CU region ownership ----------
__global__ __launch_bounds__(1024) void csr_place_kernel(const unsigned* __restrict__ packed,
                                                         const unsigned short* __restrict__ valh,
                                                         const int* __restrict__ off,
                                                         const int* __restrict__ row_start,
                                                         uint2v* __restrict__ edges) {
    __shared__ int cur[RPB];
    const int b = blockIdx.x;
    const int rbase = b * RPB;
    const int nrows = min(RPB, N_NODES - rbase);
    for (int i = threadIdx.x; i < nrows; i += 1024) cur[i] = row_start[rbase + i];
    __syncthreads();
    const int lo = off[b * L1_BLOCKS];
    const int hi = off[(b + 1) * L1_BLOCKS];         // off[32768] = N_EDGES for b=127
    for (int i = lo + (int)threadIdx.x; i < hi; i += 1024) {
        unsigned p = __builtin_nontemporal_load(packed + i);
        unsigned short vh = __builtin_nontemporal_load(valh + i);
        int lr = (int)(p >> 17);
        int c = (int)(p & 0x1FFFFu);
        int pos = atomicAdd(&cur[lr], 1);            // LDS atomic
        edges[pos] = (uint2v){(unsigned)c, ((unsigned)vh) << 16};
    }
}

// ---------- spmm: readlane broadcast + UNIFORM SGPR gather base (VALU diet) ----------
// R12 profile: 48% VALUBusy = ~17 VALU instrs/edge — 64-bit per-lane address
// math. Fix: c is a readlane result (wave-uniform) -> fold c<<8 into the
// scalar base (SALU s_lshl+s_add), per-lane offset is loop-invariant lane<<2
// -> global_load_dword v, voff, s[base]. ~6 VALU/edge remain.
__global__ __launch_bounds__(256) void spmm_csr_kernel(
    const unsigned short* __restrict__ preb, const int* __restrict__ row_start,
    const uint2v* __restrict__ edges, const float* __restrict__ bias,
    float* __restrict__ out) {
    const int lane = threadIdx.x & 63;
    const int r = blockIdx.x * 4 + (threadIdx.x >> 6);
    const int s = row_start[r];
    const int t = row_start[r + 1];
    const int n = t - s;
    float a0 = 0.f, a1 = 0.f;

    const char* pb = reinterpret_cast<const char*>(preb);
    const unsigned laneoff = (unsigned)(lane << 2);    // loop-invariant VGPR offset

    // One coalesced load grabs up to 64 edges of this row; padded lanes carry
    // {col=0, val=0} so the inner loop needs no bounds checks (0-contribution).
    uint2v ev = (uint2v){0u, 0u};
    if (lane < n) ev = edges[s + lane];
    const int nn = n < 64 ? n : 64;
    for (int j0 = 0; j0 < nn; j0 += 8) {
#pragma unroll
        for (int jj = 0; jj < 8; ++jj) {
            int j = j0 + jj;
            unsigned c = (unsigned)__builtin_amdgcn_readlane((int)ev.x, j);
            float v = __uint_as_float((unsigned)__builtin_amdgcn_readlane((int)ev.y, j));
            const char* pbase = pb + ((size_t)c << 8);           // uniform -> SALU
            unsigned g = *reinterpret_cast<const unsigned*>(pbase + laneoff);
            a0 += v * __uint_as_float(g << 16);
            a1 += v * __uint_as_float(g & 0xFFFF0000u);
        }
    }
    // Rare n > 64 fallback (cached broadcast loads).
    for (int e = s + 64; e < t; ++e) {
        uint2v cv = edges[e];
        float v = __uint_as_float(cv.y);
        const char* pbase = pb + ((size_t)cv.x << 8);
        unsigned g = *reinterpret_cast<const unsigned*>(pbase + laneoff);
        a0 += v * __uint_as_float(g << 16);
        a1 += v * __uint_as_float(g & 0xFFFF0000u);
    }

    float2 bb = *reinterpret_cast<const float2*>(bias + lane * 2);
    f32x2 o;
    o.x = fmaxf(a0 + bb.x, 0.f);
    o.y = fmaxf(a1 + bb.y, 0.f);
    __builtin_nontemporal_store(o, reinterpret_cast<f32x2*>(out + (size_t)r * F_OUT + lane * 2));
}

extern "C" void kernel_launch(void* const* d_in, const int* in_sizes, int n_in,
                              void* d_out, int out_size, void* d_ws, size_t ws_size,
                              hipStream_t stream) {
    const float* x    = (const float*)d_in[0];
    const float* W    = (const float*)d_in[1];
    const float* b    = (const float*)d_in[2];
    const float* vals = (const float*)d_in[3];
    const int*   row  = (const int*)d_in[4];
    const int*   col  = (const int*)d_in[5];
    float* out = (float*)d_out;

    // Workspace layout, total 49,531,904 B (<= 51,265,536 proven available in R1):
    char* ws = (char*)d_ws;
    unsigned short* preb      = (unsigned short*)(ws);                 // 25,600,000
    unsigned short* Wsw       = (unsigned short*)(ws + 25600000);      //     65,536
    int*            row_start = (int*)(ws + 25665536);                 //    400,016
    int*            deg       = (int*)(ws + 26065568);                 //    400,000
    int*            bsums     = (int*)(ws + 26465568);                 //      4,096
    int*            cnt       = (int*)(ws + 26469664);                 //    131,072 (16B-aligned)
    int*            off       = (int*)(ws + 26600736);                 //    131,076 (+pad)
    unsigned*       packed    = (unsigned*)(ws + 26731904);            //  6,400,000
    unsigned short* valh      = (unsigned short*)(ws + 33131904);      //  3,200,000
    uint2v*         edges     = (uint2v*)(ws + 36331904);              // 12,800,000 (8B-aligned)

    wprep_kernel<<<128, 256, 0, stream>>>(W, Wsw);
    gemm_kernel<<<N_NODES / 16, 64, 0, stream>>>(x, Wsw, preb);

    passA_kernel<<<L1_BLOCKS, L1_THREADS, 0, stream>>>(row, cnt);
    scan32768_kernel<<<1, 1024, 0, stream>>>(cnt, off);
    passB_kernel<<<L1_BLOCKS, L1_THREADS, 0, stream>>>(row, col, vals, off, packed, valh);

    bin_deg_kernel<<<N_BINS, 1024, 0, stream>>>(packed, off, deg);
    scan_block_kernel<<<SCAN_BLOCKS, 256, 0, stream>>>(deg, row_start, bsums);
    scan_bsums_kernel<<<1, 512, 0, stream>>>(bsums);
    scan_add_kernel<<<SCAN_BLOCKS, 256, 0, stream>>>(row_start, bsums);

    csr_place_kernel<<<N_BINS, 1024, 0, stream>>>(packed, valh, off, row_start, edges);

    spmm_csr_kernel<<<N_NODES / 4, 256, 0, stream>>>(preb, row_start, edges, b, out);
}

// Round 14
// 160.559 us; speedup vs baseline: 1.1252x; 1.0539x over previous
//
#include <hip/hip_runtime.h>
#include <hip/hip_bf16.h>

#define N_NODES 100000
#define N_EDGES 1600000
#define F_IN 256
#define F_OUT 128

#define N_BINS 128
#define RPB 782                  // rows per bin: 128*782 = 100096 >= 100000
#define L1_BLOCKS 256
#define L1_THREADS 512
#define L1_EDGES (N_EDGES / L1_BLOCKS)   // 6250 exactly
#define CNT_SIZE (N_BINS * L1_BLOCKS)    // 32768

typedef __attribute__((ext_vector_type(8))) short short8;
typedef __attribute__((ext_vector_type(4))) float f32x4;
typedef __attribute__((ext_vector_type(2))) float f32x2;
typedef __attribute__((ext_vector_type(2))) unsigned int uint2v;

static __device__ __forceinline__ unsigned short bf16b(float f) {
    __hip_bfloat16 h = __float2bfloat16(f);
    return *reinterpret_cast<unsigned short*>(&h);
}

// ---------- Kernel 1: pack W [256][128] f32 -> bf16 [ks(8)][kk(4)][col(128)][e(8)] ----------
__global__ void wprep_kernel(const float* __restrict__ W, unsigned short* __restrict__ Wsw) {
    int idx = blockIdx.x * 256 + threadIdx.x;   // 0..32767
    int e  = idx & 7;
    int col = (idx >> 3) & 127;
    int kk = (idx >> 10) & 3;
    int ks = idx >> 12;
    int k = ks * 32 + kk * 8 + e;
    Wsw[idx] = bf16b(W[k * 128 + col]);
}

// ---------- Kernel 2: pre = bf16(x @ W) — single-wave blocks, 16 rows, 16KB LDS ----------
// 10 independent 1-wave pipelines per CU; stage via global_load_lds (linear LDS
// dest), source granule pre-swizzled lane^j, read addr ^ (l15<<4). R12: works.
__global__ __launch_bounds__(64) void gemm_kernel(const float* __restrict__ x,
                                                  const unsigned short* __restrict__ Wsw,
                                                  unsigned short* __restrict__ preb) {
    __shared__ char sx[16384];                   // [16 rows][1024 B], swizzled
    const int lane = threadIdx.x;                // 0..63
    const int m0 = blockIdx.x * 16;              // 6250*16 = 100000 exactly: no guards
    const int l15 = lane & 15;
    const int kk = lane >> 4;

#pragma unroll
    for (int j = 0; j < 16; ++j) {
        const char* gsrc = reinterpret_cast<const char*>(x + (size_t)(m0 + j) * F_IN)
                         + ((lane ^ j) << 4);    // pre-swizzled source granule
        __builtin_amdgcn_global_load_lds(
            (const __attribute__((address_space(1))) void*)gsrc,
            (__attribute__((address_space(3))) void*)(sx + j * 1024),
            16, 0, 0);
    }
    __syncthreads();                             // 1-wave block: just the vmcnt drain

    f32x4 acc[8];
#pragma unroll
    for (int i = 0; i < 8; ++i) acc[i] = (f32x4){0.f, 0.f, 0.f, 0.f};

    const char* swb = sx + l15 * 1024;
    const int sw = l15 << 4;
#pragma unroll
    for (int ks = 0; ks < 8; ++ks) {
        const int cb = ks * 128 + kk * 32;       // byte col of this lane's 8 f32
        float4 fa = *reinterpret_cast<const float4*>(swb + ((cb) ^ sw));
        float4 fb = *reinterpret_cast<const float4*>(swb + ((cb + 16) ^ sw));
        short8 a;
        a[0] = (short)bf16b(fa.x); a[1] = (short)bf16b(fa.y);
        a[2] = (short)bf16b(fa.z); a[3] = (short)bf16b(fa.w);
        a[4] = (short)bf16b(fb.x); a[5] = (short)bf16b(fb.y);
        a[6] = (short)bf16b(fb.z); a[7] = (short)bf16b(fb.w);
        const short8* wv = reinterpret_cast<const short8*>(Wsw) + ((ks * 4 + kk) * 128 + l15);
#pragma unroll
        for (int nf = 0; nf < 8; ++nf) {
            short8 b = wv[nf * 16];
            acc[nf] = __builtin_amdgcn_mfma_f32_16x16x32_bf16(a, b, acc[nf], 0, 0, 0);
        }
    }

    // C/D layout: col = lane&15, row = (lane>>4)*4 + reg
    const int rbase = m0 + (lane >> 4) * 4;
#pragma unroll
    for (int nf = 0; nf < 8; ++nf) {
        int cc = nf * 16 + l15;
#pragma unroll
        for (int reg = 0; reg < 4; ++reg) {
            preb[(long)(rbase + reg) * F_OUT + cc] = bf16b(acc[nf][reg]);
        }
    }
}

// ---------- passA: per-(bin, block) counts — NO global atomics at all ----------
__global__ __launch_bounds__(L1_THREADS) void passA_kernel(const int* __restrict__ row,
                                                           int* __restrict__ cnt) {
    __shared__ int h[N_BINS];
    if (threadIdx.x < N_BINS) h[threadIdx.x] = 0;
    __syncthreads();
    const int g = blockIdx.x;
    const int base = g * L1_EDGES;
    for (int i = threadIdx.x; i < L1_EDGES; i += L1_THREADS) {
        int r = __builtin_nontemporal_load(row + base + i);
        atomicAdd(&h[r / RPB], 1);                   // LDS only
    }
    __syncthreads();
    if (threadIdx.x < N_BINS)
        cnt[threadIdx.x * L1_BLOCKS + g] = h[threadIdx.x];   // bin-major regions
}

// ---------- scan32768: exclusive scan of cnt[128][256] -> off[32769] ----------
__global__ void scan32768_kernel(const int* __restrict__ cnt, int* __restrict__ off) {
    __shared__ int tmp[1024];
    int t = threadIdx.x;                             // 1024 threads x 32 elems
    const int4* c4 = reinterpret_cast<const int4*>(cnt);
    int sum = 0;
#pragma unroll
    for (int j = 0; j < 8; ++j) {
        int4 v = c4[t * 8 + j];
        sum += v.x + v.y + v.z + v.w;
    }
    tmp[t] = sum;
    __syncthreads();
#pragma unroll
    for (int o = 1; o < 1024; o <<= 1) {
        int u = (t >= o) ? tmp[t - o] : 0;
        __syncthreads();
        tmp[t] += u;
        __syncthreads();
    }
    int base = tmp[t] - sum;                         // exclusive over threads
#pragma unroll
    for (int j = 0; j < 8; ++j) {
        int4 v = c4[t * 8 + j];
        off[t * 32 + j * 4 + 0] = base; base += v.x;
        off[t * 32 + j * 4 + 1] = base; base += v.y;
        off[t * 32 + j * 4 + 2] = base; base += v.z;
        off[t * 32 + j * 4 + 3] = base; base += v.w;
    }
    if (t == 1023) off[CNT_SIZE] = base;             // = N_EDGES
}

// ---------- passB: append to pre-reserved (bin, block) sub-regions; LDS-only cursors ----------
__global__ __launch_bounds__(L1_THREADS) void passB_kernel(const int* __restrict__ row,
                                                           const int* __restrict__ col,
                                                           const float* __restrict__ vals,
                                                           const int* __restrict__ off,
                                                           unsigned* __restrict__ packed,
                                                           unsigned short* __restrict__ valh) {
    __shared__ int cur[N_BINS];
    const int g = blockIdx.x;
    if (threadIdx.x < N_BINS) cur[threadIdx.x] = off[threadIdx.x * L1_BLOCKS + g];
    __syncthreads();
    const int base = g * L1_EDGES;
    for (int i = threadIdx.x; i < L1_EDGES; i += L1_THREADS) {
        int e = base + i;
        int r = __builtin_nontemporal_load(row + e);
        int c = __builtin_nontemporal_load(col + e);
        float v = __builtin_nontemporal_load(vals + e);
        int bin = r / RPB;
        int lr = r - bin * RPB;                      // < 782, 10 bits
        int pos = atomicAdd(&cur[bin], 1);           // LDS atomic
        packed[pos] = (unsigned)c | ((unsigned)lr << 17);
        valh[pos] = bf16b(v);
    }
}

// ---------- csr_fused: hist + LOCAL scan + place + row_start, ONE kernel ----------
// Key insight: bins are ordered by row range, so row_start for bin b's first
// row IS off[b*256] (=lo). Block b: LDS degree hist over its 50KB slice ->
// block-local exclusive scan (1 elem/thread, 1024 >= 782) -> absolute cursors
// = lo + scan -> write row_start AND place edges. Replaces bin_deg + 3 scan
// kernels + csr_place (4 launches + deg round-trip gone). Single-block bin
// ownership (full-line WB) preserved. Slice read twice: 2nd pass is L2-hot.
__global__ __launch_bounds__(1024) void csr_fused_kernel(const unsigned* __restrict__ packed,
                                                         const unsigned short* __restrict__ valh,
                                                         const int* __restrict__ off,
                                                         int* __restrict__ row_start,
                                                         uint2v* __restrict__ edges) {
    __shared__ int tmp[1024];
    const int b = blockIdx.x;
    const int t = threadIdx.x;
    const int rbase = b * RPB;
    const int nrows = min(RPB, N_NODES - rbase);
    const int lo = off[b * L1_BLOCKS];
    const int hi = off[(b + 1) * L1_BLOCKS];         // off[32768] = N_EDGES for b=127

    tmp[t] = 0;
    __syncthreads();
    for (int i = lo + t; i < hi; i += 1024)          // pass 1: degree histogram
        atomicAdd(&tmp[packed[i] >> 17], 1);
    __syncthreads();

    int d = tmp[t];                                  // own degree (1 elem/thread)
#pragma unroll
    for (int o = 1; o < 1024; o <<= 1) {             // inclusive Hillis-Steele
        int u = (t >= o) ? tmp[t - o] : 0;
        __syncthreads();
        tmp[t] += u;
        __syncthreads();
    }
    int excl = lo + tmp[t] - d;                      // absolute CSR start for row t
    if (t < nrows) row_start[rbase + t] = excl;
    if (b == N_BINS - 1 && t == 0) row_start[N_NODES] = N_EDGES;
    tmp[t] = excl;                                   // own slot only: no race
    __syncthreads();

    for (int i = lo + t; i < hi; i += 1024) {        // pass 2: place (L2-hot)
        unsigned p = packed[i];
        unsigned short vh = valh[i];
        int pos = atomicAdd(&tmp[p >> 17], 1);       // LDS cursor
        edges[pos] = (uint2v){p & 0x1FFFFu, ((unsigned)vh) << 16};
    }
}

// ---------- spmm: readlane broadcast + uniform SGPR gather base (unchanged: control) ----------
__global__ __launch_bounds__(256) void spmm_csr_kernel(
    const unsigned short* __restrict__ preb, const int* __restrict__ row_start,
    const uint2v* __restrict__ edges, const float* __restrict__ bias,
    float* __restrict__ out) {
    const int lane = threadIdx.x & 63;
    const int r = blockIdx.x * 4 + (threadIdx.x >> 6);
    const int s = row_start[r];
    const int t = row_start[r + 1];
    const int n = t - s;
    float a0 = 0.f, a1 = 0.f;

    const char* pb = reinterpret_cast<const char*>(preb);
    const unsigned laneoff = (unsigned)(lane << 2);    // loop-invariant VGPR offset

    uint2v ev = (uint2v){0u, 0u};
    if (lane < n) ev = edges[s + lane];
    const int nn = n < 64 ? n : 64;
    for (int j0 = 0; j0 < nn; j0 += 8) {
#pragma unroll
        for (int jj = 0; jj < 8; ++jj) {
            int j = j0 + jj;
            unsigned c = (unsigned)__builtin_amdgcn_readlane((int)ev.x, j);
            float v = __uint_as_float((unsigned)__builtin_amdgcn_readlane((int)ev.y, j));
            const char* pbase = pb + ((size_t)c << 8);           // uniform -> SALU
            unsigned g = *reinterpret_cast<const unsigned*>(pbase + laneoff);
            a0 += v * __uint_as_float(g << 16);
            a1 += v * __uint_as_float(g & 0xFFFF0000u);
        }
    }
    for (int e = s + 64; e < t; ++e) {
        uint2v cv = edges[e];
        float v = __uint_as_float(cv.y);
        const char* pbase = pb + ((size_t)cv.x << 8);
        unsigned g = *reinterpret_cast<const unsigned*>(pbase + laneoff);
        a0 += v * __uint_as_float(g << 16);
        a1 += v * __uint_as_float(g & 0xFFFF0000u);
    }

    float2 bb = *reinterpret_cast<const float2*>(bias + lane * 2);
    f32x2 o;
    o.x = fmaxf(a0 + bb.x, 0.f);
    o.y = fmaxf(a1 + bb.y, 0.f);
    __builtin_nontemporal_store(o, reinterpret_cast<f32x2*>(out + (size_t)r * F_OUT + lane * 2));
}

extern "C" void kernel_launch(void* const* d_in, const int* in_sizes, int n_in,
                              void* d_out, int out_size, void* d_ws, size_t ws_size,
                              hipStream_t stream) {
    const float* x    = (const float*)d_in[0];
    const float* W    = (const float*)d_in[1];
    const float* b    = (const float*)d_in[2];
    const float* vals = (const float*)d_in[3];
    const int*   row  = (const int*)d_in[4];
    const int*   col  = (const int*)d_in[5];
    float* out = (float*)d_out;

    // Workspace layout (deg/bsums retired), <= 51,265,536 proven available in R1:
    char* ws = (char*)d_ws;
    unsigned short* preb      = (unsigned short*)(ws);                 // 25,600,000
    unsigned short* Wsw       = (unsigned short*)(ws + 25600000);      //     65,536
    int*            row_start = (int*)(ws + 25665536);                 //    400,016
    int*            cnt       = (int*)(ws + 26469664);                 //    131,072 (16B-aligned)
    int*            off       = (int*)(ws + 26600736);                 //    131,076 (+pad)
    unsigned*       packed    = (unsigned*)(ws + 26731904);            //  6,400,000
    unsigned short* valh      = (unsigned short*)(ws + 33131904);      //  3,200,000
    uint2v*         edges     = (uint2v*)(ws + 36331904);              // 12,800,000 (8B-aligned)

    wprep_kernel<<<128, 256, 0, stream>>>(W, Wsw);
    gemm_kernel<<<N_NODES / 16, 64, 0, stream>>>(x, Wsw, preb);

    passA_kernel<<<L1_BLOCKS, L1_THREADS, 0, stream>>>(row, cnt);
    scan32768_kernel<<<1, 1024, 0, stream>>>(cnt, off);
    passB_kernel<<<L1_BLOCKS, L1_THREADS, 0, stream>>>(row, col, vals, off, packed, valh);

    csr_fused_kernel<<<N_BINS, 1024, 0, stream>>>(packed, valh, off, row_start, edges);

    spmm_csr_kernel<<<N_NODES / 4, 256, 0, stream>>>(preb, row_start, edges, b, out);
}